// Round 5
// baseline (652.783 us; speedup 1.0000x reference)
//
#include <hip/hip_runtime.h>

#define NQ 8
#define KCODES 1024
#define D 64
#define CHUNK 128
#define NCHUNK 8
#define TPB 512
#define TOKPB 64             // tokens per block (4 groups x 16)

using short8 = __attribute__((ext_vector_type(8))) short;
using f32x4  = __attribute__((ext_vector_type(4))) float;

#define GLOBAL_AS __attribute__((address_space(1)))
#define LDS_AS    __attribute__((address_space(3)))

static __device__ __forceinline__ unsigned bf16_rne_bits(float f) {
    unsigned u = __float_as_uint(f);
    return (u + 0x7fffu + ((u >> 16) & 1u)) >> 16;   // bf16 RNE bit pattern
}

// ---------------- prologue 1: split codebook into bf16 hi/lo granules ----------------
// ws_cb layout: [q][chunk][plane][code_in_chunk], plane = term*8 + kt*4 + g.
__global__ __launch_bounds__(256) void prep_cb(const float* __restrict__ cb,
                                               int4* __restrict__ ws_cb) {
    int id = blockIdx.x * 256 + threadIdx.x;       // 0 .. 131071
    int slot = id & 2047;
    int qc = id >> 11;
    int q = qc >> 3, ch = qc & 7;
    int plane = slot >> 7, n_rel = slot & 127;
    int g = plane & 3, kt = (plane >> 2) & 1, term = plane >> 3;
    int n = ch * CHUNK + n_rel;
    const float* src = cb + ((size_t)(q * KCODES + n)) * D + kt * 32 + g * 8;
    union { short s[8]; int4 v; } u;
    #pragma unroll
    for (int j = 0; j < 8; ++j) {
        float f = src[j];
        unsigned hb = bf16_rne_bits(f);
        if (term == 0) {
            u.s[j] = (short)hb;
        } else {
            float lo = f - __uint_as_float(hb << 16);
            u.s[j] = (short)bf16_rne_bits(lo);
        }
    }
    ws_cb[id] = u.v;
}

// ---------------- prologue 2: c_sq (exact, refine) + seed (-csq/2, approx) ----------------
__global__ __launch_bounds__(256) void prep_csq(const float* __restrict__ cb,
                                                float* __restrict__ ws_csq,
                                                float* __restrict__ ws_csqh) {
    int id = blockIdx.x * 256 + threadIdx.x;       // 0 .. 8191
    const float* c = cb + (size_t)id * D;
    float s0 = 0.f, s1 = 0.f, s2 = 0.f, s3 = 0.f;
    #pragma unroll
    for (int j = 0; j < 16; ++j) {
        s0 = fmaf(c[4*j+0], c[4*j+0], s0);
        s1 = fmaf(c[4*j+1], c[4*j+1], s1);
        s2 = fmaf(c[4*j+2], c[4*j+2], s2);
        s3 = fmaf(c[4*j+3], c[4*j+3], s3);
    }
    float cs = (s0 + s1) + (s2 + s3);
    ws_csq[id]  = cs;
    ws_csqh[id] = -0.5f * cs;
}

// ---------------- main kernel ----------------
// Wave pair (group, half): 16 tokens, half of each chunk's codes (4 of 8 tiles).
__global__ __launch_bounds__(TPB, 8) void rvq_mfma(
    const float* __restrict__ x,
    const float* __restrict__ cb,
    const int4* __restrict__ ws_cb,
    const float* __restrict__ ws_csq,
    const float* __restrict__ ws_csqh,
    float* __restrict__ out)
{
    // chunk staging (32768 B) aliases refine residual buffer (64*68*4 = 17408 B)
    __shared__ __align__(16) char smem[32768];
    float* lds_resid = (float*)smem;
    __shared__ float lds_csqh[CHUNK];
    __shared__ int4  lds_cand[8 * 16];    // [group*2+half][token16]
    __shared__ int   lds_pick[TOKPB];

    const int tid   = threadIdx.x;
    const int lane  = tid & 63;
    const int wave  = tid >> 6;          // 0..7
    const int group = wave >> 1;         // 0..3  (token group)
    const int half  = wave & 1;          // 0..1  (code half: tiles half*4..half*4+3)
    const int g     = lane >> 4;         // quad
    const int c     = lane & 15;
    const int ltok  = group * 16 + c;    // token within block
    const int tok   = blockIdx.x * TOKPB + ltok;

    const float4* xp = (const float4*)(x + (size_t)tok * D);
    float4 rv0 = xp[g*2], rv1 = xp[g*2+1], rv2 = xp[8+g*2], rv3 = xp[8+g*2+1];

    // static LDS base for B-fragment reads (compile-time ds_read offsets off this)
    const char* bp = smem + (c << 4) + (g << 11) + (half << 10);

    for (int q = 0; q < NQ; ++q) {
        // ---- split residual into bf16 hi/lo A-fragments ----
        short8 ah0, al0, ah1, al1;
        {
            const float* fv0 = (const float*)&rv0;
            const float* fv1 = (const float*)&rv1;
            const float* fv2 = (const float*)&rv2;
            const float* fv3 = (const float*)&rv3;
            #pragma unroll
            for (int j = 0; j < 4; ++j) {
                float a = fv0[j], b = fv1[j], e = fv2[j], f = fv3[j];
                unsigned ha = bf16_rne_bits(a);
                unsigned hbv = bf16_rne_bits(b);
                unsigned he = bf16_rne_bits(e);
                unsigned hf = bf16_rne_bits(f);
                ah0[j]   = (short)ha;  ah0[4+j] = (short)hbv;
                ah1[j]   = (short)he;  ah1[4+j] = (short)hf;
                al0[j]   = (short)bf16_rne_bits(a - __uint_as_float(ha  << 16));
                al0[4+j] = (short)bf16_rne_bits(b - __uint_as_float(hbv << 16));
                al1[j]   = (short)bf16_rne_bits(e - __uint_as_float(he  << 16));
                al1[4+j] = (short)bf16_rne_bits(f - __uint_as_float(hf  << 16));
            }
        }

        // argmax of v = dot - csq/2 ; track top-2 per r with indices
        float d1[4], d2[4]; int i1[4], i2[4];
        #pragma unroll
        for (int r = 0; r < 4; ++r) { d1[r] = -3.0e38f; d2[r] = -3.0e38f; i1[r] = 0; i2[r] = 0; }

        for (int ch = 0; ch < NCHUNK; ++ch) {
            __syncthreads();   // all waves done reading previous chunk / refine buffer
            {
                // async global->LDS staging: 512 thr x 4 x 16B = 32 KB, linear
                const int4* src = ws_cb + (size_t)(q * NCHUNK + ch) * 2048 + tid;
                LDS_AS char* ldst = (LDS_AS char*)(smem) + tid * 16;
                #pragma unroll
                for (int t = 0; t < 4; ++t) {
                    __builtin_amdgcn_global_load_lds(
                        (const GLOBAL_AS unsigned int*)(src + t * TPB),
                        (LDS_AS unsigned int*)(ldst + t * TPB * 16), 16, 0, 0);
                }
                if (tid < CHUNK) {
                    __builtin_amdgcn_global_load_lds(
                        (const GLOBAL_AS unsigned int*)(ws_csqh + q * KCODES + ch * CHUNK + tid),
                        (LDS_AS unsigned int*)(&lds_csqh[tid]), 4, 0, 0);
                }
            }
            __syncthreads();   // drains vmcnt -> LDS visible

            const int code_base = ch * CHUNK + half * 64 + c;
            #pragma unroll
            for (int tt = 0; tt < 4; ++tt) {
                // compile-time ds_read offsets off bp
                short8 bh0 = *(const short8*)(bp + tt * 256);
                short8 bh1 = *(const short8*)(bp + 8192  + tt * 256);
                short8 bl0 = *(const short8*)(bp + 16384 + tt * 256);
                short8 bl1 = *(const short8*)(bp + 24576 + tt * 256);
                const float sd = lds_csqh[half * 64 + tt * 16 + c];
                f32x4 acc = {sd, sd, sd, sd};
                acc = __builtin_amdgcn_mfma_f32_16x16x32_bf16(ah0, bh0, acc, 0, 0, 0);
                acc = __builtin_amdgcn_mfma_f32_16x16x32_bf16(ah1, bh1, acc, 0, 0, 0);
                acc = __builtin_amdgcn_mfma_f32_16x16x32_bf16(al0, bh0, acc, 0, 0, 0);
                acc = __builtin_amdgcn_mfma_f32_16x16x32_bf16(ah0, bl0, acc, 0, 0, 0);
                acc = __builtin_amdgcn_mfma_f32_16x16x32_bf16(al1, bh1, acc, 0, 0, 0);
                acc = __builtin_amdgcn_mfma_f32_16x16x32_bf16(ah1, bl1, acc, 0, 0, 0);
                acc = __builtin_amdgcn_mfma_f32_16x16x32_bf16(al0, bl0, acc, 0, 0, 0);
                acc = __builtin_amdgcn_mfma_f32_16x16x32_bf16(al1, bl1, acc, 0, 0, 0);

                const int codev = code_base + tt * 16;
                #pragma unroll
                for (int r = 0; r < 4; ++r) {
                    float v = acc[r];
                    bool gt1 = v > d1[r];
                    bool gt2 = v > d2[r];
                    // med3 trick: d2' = median(d1, d2, v)  (exact for sorted d1>=d2)
                    float nd2 = fmaxf(fminf(d1[r], v), d2[r]);   // = med3
                    d1[r] = fmaxf(v, d1[r]);
                    d2[r] = nd2;
                    i2[r] = gt2 ? (gt1 ? i1[r] : codev) : i2[r];
                    i1[r] = gt1 ? codev : i1[r];
                }
            }
        }

        // ---- cross-lane top-2 merge over the 16 c-lanes (lexicographic, max-form) ----
        #pragma unroll
        for (int s = 1; s <= 8; s <<= 1) {
            #pragma unroll
            for (int r = 0; r < 4; ++r) {
                float od1 = __shfl_xor(d1[r], s);
                int   oi1 = __shfl_xor(i1[r], s);
                float od2 = __shfl_xor(d2[r], s);
                int   oi2 = __shfl_xor(i2[r], s);
                bool keep = (d1[r] > od1) || (d1[r] == od1 && i1[r] < oi1);
                float w1 = keep ? d1[r] : od1;  int wi1 = keep ? i1[r] : oi1;
                float l1 = keep ? od1 : d1[r];  int li1 = keep ? oi1 : i1[r];
                bool bsec = (od2 > d2[r]) || (od2 == d2[r] && oi2 < i2[r]);
                float y  = bsec ? od2 : d2[r];  int yi = bsec ? oi2 : i2[r];
                bool xw  = (l1 > y) || (l1 == y && li1 < yi);
                d2[r] = xw ? l1 : y;  i2[r] = xw ? li1 : yi;
                d1[r] = w1; i1[r] = wi1;
            }
        }

        // ---- publish per-half candidates + residual to LDS ----
        __syncthreads();                     // all waves done reading chunk buffer
        if (c == 0) {
            #pragma unroll
            for (int r = 0; r < 4; ++r)
                lds_cand[(group * 2 + half) * 16 + g * 4 + r] =
                    make_int4(__float_as_int(d1[r]), i1[r], __float_as_int(d2[r]), i2[r]);
        }
        if (half == 0) {
            float* rr = lds_resid + (size_t)ltok * 68;
            *(float4*)(rr + 8*g)      = rv0;
            *(float4*)(rr + 8*g + 4)  = rv1;
            *(float4*)(rr + 32 + 8*g) = rv2;
            *(float4*)(rr + 36 + 8*g) = rv3;
        }
        __syncthreads();

        // ---- cross-half merge + ALWAYS-ON exact refinement (even waves, 32 lanes) ----
        if (half == 0) {
            const int t   = (lane >> 1) & 15;      // token within group
            const int sel = lane & 1;
            const int4 A = lds_cand[(group * 2 + 0) * 16 + t];
            const int4 B = lds_cand[(group * 2 + 1) * 16 + t];
            float a1 = __int_as_float(A.x), a2 = __int_as_float(A.z);
            float b1 = __int_as_float(B.x), b2 = __int_as_float(B.z);
            int ai1 = A.y, ai2 = A.w, bi1 = B.y, bi2 = B.w;
            // merged top-2 of {a1,a2} U {b1,b2} (each pair sorted desc), lexicographic
            bool keep = (a1 > b1) || (a1 == b1 && ai1 < bi1);
            float m1 = keep ? a1 : b1;  int mi1 = keep ? ai1 : bi1;
            float l1 = keep ? b1 : a1;  int li1 = keep ? bi1 : ai1;
            float s2 = keep ? a2 : b2;  int si2 = keep ? ai2 : bi2;
            bool xw = (l1 > s2) || (l1 == s2 && li1 < si2);
            float m2 = xw ? l1 : s2;    int mi2 = xw ? li1 : si2;
            (void)m1; (void)m2;

            const int cd = sel ? mi2 : mi1;
            const float4* rrv = (const float4*)(lds_resid + (size_t)(group * 16 + t) * 68);
            const float4* cpv = (const float4*)(cb + ((size_t)(q * KCODES + cd)) * D);
            float ax = 0.f, ay = 0.f, az = 0.f, aw = 0.f;
            #pragma unroll
            for (int j = 0; j < 16; ++j) {
                float4 rv = rrv[j];
                float4 cv = cpv[j];
                ax = fmaf(rv.x, cv.x, ax);
                ay = fmaf(rv.y, cv.y, ay);
                az = fmaf(rv.z, cv.z, az);
                aw = fmaf(rv.w, cv.w, aw);
            }
            float dot = (ax + ay) + (az + aw);
            float dd = fmaf(dot, -2.0f, ws_csq[q * KCODES + cd]);
            float od = __shfl_xor(dd, 1);
            float dA = sel ? od : dd;   // d(mi1)
            float dB = sel ? dd : od;   // d(mi2)
            int lo  = mi1 < mi2 ? mi1 : mi2;
            int hi  = mi1 < mi2 ? mi2 : mi1;
            float dlo = mi1 < mi2 ? dA : dB;
            float dhi = mi1 < mi2 ? dB : dA;
            int pick = (dhi < dlo) ? hi : lo;  // strict-<, lower index wins ties
            if (lane < 32 && sel == 0) lds_pick[group * 16 + t] = pick;
        }
        __syncthreads();
        const int ifin = lds_pick[ltok];

        // ---- residual update (both halves identically): r -= cb[q][ifin] ----
        {
            const float4* cp = (const float4*)(cb + ((size_t)(q * KCODES + ifin)) * D);
            float4 c0 = cp[g*2], c1 = cp[g*2+1], c2 = cp[8+g*2], c3 = cp[8+g*2+1];
            rv0.x -= c0.x; rv0.y -= c0.y; rv0.z -= c0.z; rv0.w -= c0.w;
            rv1.x -= c1.x; rv1.y -= c1.y; rv1.z -= c1.z; rv1.w -= c1.w;
            rv2.x -= c2.x; rv2.y -= c2.y; rv2.z -= c2.z; rv2.w -= c2.w;
            rv3.x -= c3.x; rv3.y -= c3.y; rv3.z -= c3.z; rv3.w -= c3.w;
        }
    }

    // ---- epilogue: out = x - residual_final (one half writes) ----
    if (half == 0) {
        float4* op = (float4*)(out + (size_t)tok * D);
        float4 xv0 = xp[g*2], xv1 = xp[g*2+1], xv2 = xp[8+g*2], xv3 = xp[8+g*2+1];
        float4 o0, o1, o2, o3;
        o0.x = xv0.x - rv0.x; o0.y = xv0.y - rv0.y; o0.z = xv0.z - rv0.z; o0.w = xv0.w - rv0.w;
        o1.x = xv1.x - rv1.x; o1.y = xv1.y - rv1.y; o1.z = xv1.z - rv1.z; o1.w = xv1.w - rv1.w;
        o2.x = xv2.x - rv2.x; o2.y = xv2.y - rv2.y; o2.z = xv2.z - rv2.z; o2.w = xv2.w - rv2.w;
        o3.x = xv3.x - rv3.x; o3.y = xv3.y - rv3.y; o3.z = xv3.z - rv3.z; o3.w = xv3.w - rv3.w;
        op[g*2] = o0; op[g*2+1] = o1; op[8+g*2] = o2; op[8+g*2+1] = o3;
    }
}

extern "C" void kernel_launch(void* const* d_in, const int* in_sizes, int n_in,
                              void* d_out, int out_size, void* d_ws, size_t ws_size,
                              hipStream_t stream) {
    const float* x  = (const float*)d_in[0];
    const float* cb = (const float*)d_in[1];
    float* out = (float*)d_out;

    int4*  ws_cb   = (int4*)d_ws;                                      // 2 MB
    float* ws_csq  = (float*)((char*)d_ws + (size_t)2 * 1024 * 1024);  // 32 KB
    float* ws_csqh = ws_csq + 8192;                                    // 32 KB

    prep_cb <<<512, 256, 0, stream>>>(cb, ws_cb);
    prep_csq<<< 32, 256, 0, stream>>>(cb, ws_csq, ws_csqh);

    const int n_tokens = in_sizes[0] / D;            // 65536
    const int grid = n_tokens / TOKPB;               // 1024 blocks
    rvq_mfma<<<grid, TPB, 0, stream>>>(x, cb, ws_cb, ws_csq, ws_csqh, out);
}

// Round 6
// 530.476 us; speedup vs baseline: 1.2306x; 1.2306x over previous
//
#include <hip/hip_runtime.h>

#define NQ 8
#define KCODES 1024
#define D 64
#define CHUNK 128
#define NCHUNK 8
#define TPB 512
#define TOKPB 64             // tokens per block (4 groups x 16)
#define BIAS 96.0f

using short8 = __attribute__((ext_vector_type(8))) short;
using f32x4  = __attribute__((ext_vector_type(4))) float;

#define GLOBAL_AS __attribute__((address_space(1)))
#define LDS_AS    __attribute__((address_space(3)))

static __device__ __forceinline__ unsigned bf16_rne_bits(float f) {
    unsigned u = __float_as_uint(f);
    return (u + 0x7fffu + ((u >> 16) & 1u)) >> 16;   // bf16 RNE bit pattern
}
static __device__ __forceinline__ unsigned umn(unsigned a, unsigned b) { return a < b ? a : b; }
static __device__ __forceinline__ unsigned umx(unsigned a, unsigned b) { return a > b ? a : b; }
static __device__ __forceinline__ unsigned umed3(unsigned a, unsigned b, unsigned c) {
    return umx(umn(a, b), umn(umx(a, b), c));
}

// ---------------- prologue 1: split NEGATED codebook into bf16 hi/lo granules ----------------
// ws_cb layout: [q][chunk][plane][code_in_chunk], plane = term*8 + kt*4 + g.
// Stores -c so MFMA accumulates  seed - dot.
__global__ __launch_bounds__(256) void prep_cb(const float* __restrict__ cb,
                                               int4* __restrict__ ws_cb) {
    int id = blockIdx.x * 256 + threadIdx.x;       // 0 .. 131071
    int slot = id & 2047;
    int qc = id >> 11;
    int q = qc >> 3, ch = qc & 7;
    int plane = slot >> 7, n_rel = slot & 127;
    int g = plane & 3, kt = (plane >> 2) & 1, term = plane >> 3;
    int n = ch * CHUNK + n_rel;
    const float* src = cb + ((size_t)(q * KCODES + n)) * D + kt * 32 + g * 8;
    union { short s[8]; int4 v; } u;
    #pragma unroll
    for (int j = 0; j < 8; ++j) {
        float f = -src[j];                         // NEGATED
        unsigned hb = bf16_rne_bits(f);
        if (term == 0) {
            u.s[j] = (short)hb;
        } else {
            float lo = f - __uint_as_float(hb << 16);
            u.s[j] = (short)bf16_rne_bits(lo);
        }
    }
    ws_cb[id] = u.v;
}

// ---------------- prologue 2: c_sq exact (refine) + seed (csq/2 + BIAS, approx) ----------------
__global__ __launch_bounds__(256) void prep_csq(const float* __restrict__ cb,
                                                float* __restrict__ ws_csq,
                                                float* __restrict__ ws_csqh) {
    int id = blockIdx.x * 256 + threadIdx.x;       // 0 .. 8191
    const float* c = cb + (size_t)id * D;
    float s0 = 0.f, s1 = 0.f, s2 = 0.f, s3 = 0.f;
    #pragma unroll
    for (int j = 0; j < 16; ++j) {
        s0 = fmaf(c[4*j+0], c[4*j+0], s0);
        s1 = fmaf(c[4*j+1], c[4*j+1], s1);
        s2 = fmaf(c[4*j+2], c[4*j+2], s2);
        s3 = fmaf(c[4*j+3], c[4*j+3], s3);
    }
    float cs = (s0 + s1) + (s2 + s3);
    ws_csq[id]  = cs;                // exact, refine comparator (bit-identical to r3/r4)
    ws_csqh[id] = 0.5f * cs + BIAS;  // approx seed: acc = seed - dot  (always > 0)
}

// ---------------- main kernel ----------------
// Wave (group, half): 16 tokens x half of each chunk's codes. Packed-u32 top-3 tracking.
__global__ __launch_bounds__(TPB, 6) void rvq_mfma(
    const float* __restrict__ x,
    const float* __restrict__ cb,
    const int4* __restrict__ ws_cb,
    const float* __restrict__ ws_csq,
    float* __restrict__ out)
{
    // chunk staging (32768 B) aliases refine residual buffer (64*68*4 = 17408 B)
    __shared__ __align__(16) char smem[32768];
    float* lds_resid = (float*)smem;
    __shared__ float lds_csqh[CHUNK];
    __shared__ int4  lds_cand[8 * 16];    // [group*2+half][token16] = packed top-3
    __shared__ int   lds_pick[TOKPB];

    const int tid   = threadIdx.x;
    const int lane  = tid & 63;
    const int wave  = tid >> 6;          // 0..7
    const int group = wave >> 1;         // 0..3
    const int half  = wave & 1;          // code half
    const int g     = lane >> 4;         // quad
    const int c     = lane & 15;
    const int ltok  = group * 16 + c;
    const int tok   = blockIdx.x * TOKPB + ltok;

    const float4* xp = (const float4*)(x + (size_t)tok * D);
    float4 rv0 = xp[g*2], rv1 = xp[g*2+1], rv2 = xp[8+g*2], rv3 = xp[8+g*2+1];

    // static LDS base for B-fragment reads (compile-time ds_read offsets)
    const char* bp = smem + (c << 4) + (g << 11) + (half << 10);
    const unsigned code_wc = (unsigned)(half * 64 + c);   // lane's code low bits

    for (int q = 0; q < NQ; ++q) {
        // ---- split residual into bf16 hi/lo A-fragments ----
        short8 ah0, al0, ah1, al1;
        {
            const float* fv0 = (const float*)&rv0;
            const float* fv1 = (const float*)&rv1;
            const float* fv2 = (const float*)&rv2;
            const float* fv3 = (const float*)&rv3;
            #pragma unroll
            for (int j = 0; j < 4; ++j) {
                float a = fv0[j], b = fv1[j], e = fv2[j], f = fv3[j];
                unsigned ha = bf16_rne_bits(a);
                unsigned hbv = bf16_rne_bits(b);
                unsigned he = bf16_rne_bits(e);
                unsigned hf = bf16_rne_bits(f);
                ah0[j]   = (short)ha;  ah0[4+j] = (short)hbv;
                ah1[j]   = (short)he;  ah1[4+j] = (short)hf;
                al0[j]   = (short)bf16_rne_bits(a - __uint_as_float(ha  << 16));
                al0[4+j] = (short)bf16_rne_bits(b - __uint_as_float(hbv << 16));
                al1[j]   = (short)bf16_rne_bits(e - __uint_as_float(he  << 16));
                al1[4+j] = (short)bf16_rne_bits(f - __uint_as_float(hf  << 16));
            }
        }

        // packed top-3 (ascending; bits = positive-float order == u32 order)
        unsigned t1[4], t2[4], t3[4];
        #pragma unroll
        for (int r = 0; r < 4; ++r) { t1[r] = 0xFFFFFFFFu; t2[r] = 0xFFFFFFFFu; t3[r] = 0xFFFFFFFFu; }

        for (int ch = 0; ch < NCHUNK; ++ch) {
            __syncthreads();   // all waves done with previous chunk / refine buffer
            {
                // async global->LDS staging: 512 thr x 4 x 16B = 32 KB, linear
                const int4* src = ws_cb + (size_t)(q * NCHUNK + ch) * 2048 + tid;
                LDS_AS char* ldst = (LDS_AS char*)(smem) + tid * 16;
                #pragma unroll
                for (int t = 0; t < 4; ++t) {
                    __builtin_amdgcn_global_load_lds(
                        (const GLOBAL_AS unsigned int*)(src + t * TPB),
                        (LDS_AS unsigned int*)(ldst + t * TPB * 16), 16, 0, 0);
                }
                if (tid < CHUNK) {
                    const float* csrc = ws_csq;  // dummy to keep types quiet (not used)
                    (void)csrc;
                    __builtin_amdgcn_global_load_lds(
                        (const GLOBAL_AS unsigned int*)(ws_csq + 8192 + q * KCODES + ch * CHUNK + tid),
                        (LDS_AS unsigned int*)(&lds_csqh[tid]), 4, 0, 0);
                }
            }
            __syncthreads();   // drains vmcnt -> LDS visible

            #pragma unroll
            for (int tt = 0; tt < 4; ++tt) {
                short8 bh0 = *(const short8*)(bp + tt * 256);
                short8 bh1 = *(const short8*)(bp + 8192  + tt * 256);
                short8 bl0 = *(const short8*)(bp + 16384 + tt * 256);
                short8 bl1 = *(const short8*)(bp + 24576 + tt * 256);
                const float sd = lds_csqh[half * 64 + tt * 16 + c];
                f32x4 acc = {sd, sd, sd, sd};
                acc = __builtin_amdgcn_mfma_f32_16x16x32_bf16(ah0, bh0, acc, 0, 0, 0);
                acc = __builtin_amdgcn_mfma_f32_16x16x32_bf16(ah1, bh1, acc, 0, 0, 0);
                acc = __builtin_amdgcn_mfma_f32_16x16x32_bf16(al0, bh0, acc, 0, 0, 0);
                acc = __builtin_amdgcn_mfma_f32_16x16x32_bf16(ah0, bl0, acc, 0, 0, 0);
                acc = __builtin_amdgcn_mfma_f32_16x16x32_bf16(al1, bh1, acc, 0, 0, 0);
                acc = __builtin_amdgcn_mfma_f32_16x16x32_bf16(ah1, bl1, acc, 0, 0, 0);
                acc = __builtin_amdgcn_mfma_f32_16x16x32_bf16(al0, bl0, acc, 0, 0, 0);
                acc = __builtin_amdgcn_mfma_f32_16x16x32_bf16(al1, bl1, acc, 0, 0, 0);

                // acc[r] = csq/2 + BIAS - dot  (smaller = better), strictly positive
                const unsigned codev = code_wc + (unsigned)(ch * 128 + tt * 16);
                #pragma unroll
                for (int r = 0; r < 4; ++r) {
                    unsigned p = (__float_as_uint(acc[r]) & 0xFFFFFC00u) | codev;
                    unsigned n2 = umn(t2[r], umx(t1[r], p));   // med3(t1,t2,p), t1<=t2
                    unsigned n3 = umn(t3[r], umx(t2[r], p));   // med3(t2,t3,p), t2<=t3
                    t1[r] = umn(t1[r], p);
                    t2[r] = n2;
                    t3[r] = n3;
                }
            }
        }

        // ---- cross-lane top-3 merge over the 16 c-lanes (pure u32 sorted-triple network) ----
        #pragma unroll
        for (int s = 1; s <= 8; s <<= 1) {
            #pragma unroll
            for (int r = 0; r < 4; ++r) {
                unsigned o1 = (unsigned)__shfl_xor((int)t1[r], s);
                unsigned o2 = (unsigned)__shfl_xor((int)t2[r], s);
                unsigned o3 = (unsigned)__shfl_xor((int)t3[r], s);
                unsigned x1 = umn(t1[r], o1), y1 = umx(t1[r], o1);
                unsigned x2 = umn(t2[r], o2), y2 = umx(t2[r], o2);
                unsigned x3 = umn(t3[r], o3);
                t1[r] = x1;
                t3[r] = umed3(y1, x2, umn(y2, x3));
                t2[r] = umn(y1, x2);
            }
        }

        // ---- publish per-half candidates + residual to LDS ----
        __syncthreads();                     // all waves done reading chunk buffer
        if (c == 0) {
            #pragma unroll
            for (int r = 0; r < 4; ++r)
                lds_cand[(group * 2 + half) * 16 + g * 4 + r] =
                    make_int4((int)t1[r], (int)t2[r], (int)t3[r], 0);
        }
        if (half == 0) {
            float* rr = lds_resid + (size_t)ltok * 68;
            *(float4*)(rr + 8*g)      = rv0;
            *(float4*)(rr + 8*g + 4)  = rv1;
            *(float4*)(rr + 32 + 8*g) = rv2;
            *(float4*)(rr + 36 + 8*g) = rv3;
        }
        __syncthreads();

        // ---- cross-half merge + ALWAYS-ON exact refinement over top-3 ----
        {
            const int sel = lane >> 4;         // 0..3 (3 idle-ish)
            const int t   = lane & 15;
            const int4 A = lds_cand[(group * 2 + 0) * 16 + t];
            const int4 B = lds_cand[(group * 2 + 1) * 16 + t];
            unsigned a1 = (unsigned)A.x, a2 = (unsigned)A.y, a3 = (unsigned)A.z;
            unsigned b1 = (unsigned)B.x, b2 = (unsigned)B.y, b3 = (unsigned)B.z;
            unsigned x1 = umn(a1, b1), y1 = umx(a1, b1);
            unsigned x2 = umn(a2, b2), y2 = umx(a2, b2);
            unsigned x3 = umn(a3, b3);
            unsigned m1 = x1;
            unsigned m2 = umn(y1, x2);
            unsigned m3 = umed3(y1, x2, umn(y2, x3));
            unsigned psel = (sel == 0) ? m1 : ((sel == 1) ? m2 : m3);
            const int cd = (int)(psel & 1023u);

            // exact fp32 distance, bit-identical comparator arithmetic to rounds 3/4
            const float4* rrv = (const float4*)(lds_resid + (size_t)(group * 16 + t) * 68);
            const float4* cpv = (const float4*)(cb + ((size_t)(q * KCODES + cd)) * D);
            float ax = 0.f, ay = 0.f, az = 0.f, aw = 0.f;
            #pragma unroll
            for (int j = 0; j < 16; ++j) {
                float4 rv = rrv[j];
                float4 cv = cpv[j];
                ax = fmaf(rv.x, cv.x, ax);
                ay = fmaf(rv.y, cv.y, ay);
                az = fmaf(rv.z, cv.z, az);
                aw = fmaf(rv.w, cv.w, aw);
            }
            float dot = (ax + ay) + (az + aw);
            float dd = fmaf(dot, -2.0f, ws_csq[q * KCODES + cd]);

            float d0 = __shfl(dd, t);
            float d1 = __shfl(dd, t + 16);
            float d2 = __shfl(dd, t + 32);
            int cc0 = (int)(m1 & 1023u);
            int cc1 = (int)(m2 & 1023u);
            int cc2 = (int)(m3 & 1023u);
            float db = d0; int pick = cc0;
            if (d1 < db || (d1 == db && cc1 < pick)) { db = d1; pick = cc1; }
            if (d2 < db || (d2 == db && cc2 < pick)) { db = d2; pick = cc2; }
            if (half == 0 && sel == 0) lds_pick[group * 16 + t] = pick;
        }
        __syncthreads();
        const int ifin = lds_pick[ltok];

        // ---- residual update (both halves identically): r -= cb[q][ifin] ----
        {
            const float4* cp = (const float4*)(cb + ((size_t)(q * KCODES + ifin)) * D);
            float4 c0 = cp[g*2], c1 = cp[g*2+1], c2 = cp[8+g*2], c3 = cp[8+g*2+1];
            rv0.x -= c0.x; rv0.y -= c0.y; rv0.z -= c0.z; rv0.w -= c0.w;
            rv1.x -= c1.x; rv1.y -= c1.y; rv1.z -= c1.z; rv1.w -= c1.w;
            rv2.x -= c2.x; rv2.y -= c2.y; rv2.z -= c2.z; rv2.w -= c2.w;
            rv3.x -= c3.x; rv3.y -= c3.y; rv3.z -= c3.z; rv3.w -= c3.w;
        }
    }

    // ---- epilogue: out = x - residual_final (one half writes) ----
    if (half == 0) {
        float4* op = (float4*)(out + (size_t)tok * D);
        float4 xv0 = xp[g*2], xv1 = xp[g*2+1], xv2 = xp[8+g*2], xv3 = xp[8+g*2+1];
        float4 o0, o1, o2, o3;
        o0.x = xv0.x - rv0.x; o0.y = xv0.y - rv0.y; o0.z = xv0.z - rv0.z; o0.w = xv0.w - rv0.w;
        o1.x = xv1.x - rv1.x; o1.y = xv1.y - rv1.y; o1.z = xv1.z - rv1.z; o1.w = xv1.w - rv1.w;
        o2.x = xv2.x - rv2.x; o2.y = xv2.y - rv2.y; o2.z = xv2.z - rv2.z; o2.w = xv2.w - rv2.w;
        o3.x = xv3.x - rv3.x; o3.y = xv3.y - rv3.y; o3.z = xv3.z - rv3.z; o3.w = xv3.w - rv3.w;
        op[g*2] = o0; op[g*2+1] = o1; op[8+g*2] = o2; op[8+g*2+1] = o3;
    }
}

extern "C" void kernel_launch(void* const* d_in, const int* in_sizes, int n_in,
                              void* d_out, int out_size, void* d_ws, size_t ws_size,
                              hipStream_t stream) {
    const float* x  = (const float*)d_in[0];
    const float* cb = (const float*)d_in[1];
    float* out = (float*)d_out;

    int4*  ws_cb   = (int4*)d_ws;                                      // 2 MB
    float* ws_csq  = (float*)((char*)d_ws + (size_t)2 * 1024 * 1024);  // 32 KB exact
    float* ws_csqh = ws_csq + 8192;                                    // 32 KB seed (= ws_csq+8192)

    prep_cb <<<512, 256, 0, stream>>>(cb, ws_cb);
    prep_csq<<< 32, 256, 0, stream>>>(cb, ws_csq, ws_csqh);

    const int n_tokens = in_sizes[0] / D;            // 65536
    const int grid = n_tokens / TOKPB;               // 1024 blocks
    rvq_mfma<<<grid, TPB, 0, stream>>>(x, cb, ws_cb, ws_csq, out);
}

// Round 7
// 476.186 us; speedup vs baseline: 1.3709x; 1.1140x over previous
//
#include <hip/hip_runtime.h>

#define NQ 8
#define KCODES 1024
#define D 64
#define CHUNK 128
#define NCHUNK 8
#define TPB 512
#define TOKPB 64             // tokens per block (4 groups x 16)
#define BIAS 96.0f

using short8 = __attribute__((ext_vector_type(8))) short;
using f32x4  = __attribute__((ext_vector_type(4))) float;

#define GLOBAL_AS __attribute__((address_space(1)))
#define LDS_AS    __attribute__((address_space(3)))

static __device__ __forceinline__ unsigned bf16_rne_bits(float f) {
    unsigned u = __float_as_uint(f);
    return (u + 0x7fffu + ((u >> 16) & 1u)) >> 16;   // bf16 RNE bit pattern
}
static __device__ __forceinline__ unsigned umn(unsigned a, unsigned b) { return a < b ? a : b; }
static __device__ __forceinline__ unsigned umx(unsigned a, unsigned b) { return a > b ? a : b; }
static __device__ __forceinline__ unsigned umed3(unsigned a, unsigned b, unsigned c) {
    return umx(umn(a, b), umn(umx(a, b), c));
}

// ---------------- prologue 1: split NEGATED codebook into bf16 hi/lo granules ----------------
// ws_cb layout: [q][chunk][plane][code_in_chunk], plane = term*8 + kt*4 + g. Stores -c.
__global__ __launch_bounds__(256) void prep_cb(const float* __restrict__ cb,
                                               int4* __restrict__ ws_cb) {
    int id = blockIdx.x * 256 + threadIdx.x;       // 0 .. 131071
    int slot = id & 2047;
    int qc = id >> 11;
    int q = qc >> 3, ch = qc & 7;
    int plane = slot >> 7, n_rel = slot & 127;
    int g = plane & 3, kt = (plane >> 2) & 1, term = plane >> 3;
    int n = ch * CHUNK + n_rel;
    const float* src = cb + ((size_t)(q * KCODES + n)) * D + kt * 32 + g * 8;
    union { short s[8]; int4 v; } u;
    #pragma unroll
    for (int j = 0; j < 8; ++j) {
        float f = -src[j];                         // NEGATED
        unsigned hb = bf16_rne_bits(f);
        if (term == 0) {
            u.s[j] = (short)hb;
        } else {
            float lo = f - __uint_as_float(hb << 16);
            u.s[j] = (short)bf16_rne_bits(lo);
        }
    }
    ws_cb[id] = u.v;
}

// ---------------- prologue 2: c_sq exact (refine) + seed (csq/2 + BIAS, approx) ----------------
__global__ __launch_bounds__(256) void prep_csq(const float* __restrict__ cb,
                                                float* __restrict__ ws_csq,
                                                float* __restrict__ ws_csqh) {
    int id = blockIdx.x * 256 + threadIdx.x;       // 0 .. 8191
    const float* c = cb + (size_t)id * D;
    float s0 = 0.f, s1 = 0.f, s2 = 0.f, s3 = 0.f;
    #pragma unroll
    for (int j = 0; j < 16; ++j) {
        s0 = fmaf(c[4*j+0], c[4*j+0], s0);
        s1 = fmaf(c[4*j+1], c[4*j+1], s1);
        s2 = fmaf(c[4*j+2], c[4*j+2], s2);
        s3 = fmaf(c[4*j+3], c[4*j+3], s3);
    }
    float cs = (s0 + s1) + (s2 + s3);
    ws_csq[id]  = cs;                // exact, refine comparator (bit-identical to r3/r4)
    ws_csqh[id] = 0.5f * cs + BIAS;  // approx seed: acc = seed - dot (always > 0)
}

// ---------------- main kernel ----------------
// Residual lives in LDS for the whole kernel; hot loop holds only A-frags + packed top-3.
__global__ __launch_bounds__(TPB, 5) void rvq_mfma(
    const float* __restrict__ x,
    const float* __restrict__ cb,
    const int4* __restrict__ ws_cb,
    const float* __restrict__ ws_csq,
    float* __restrict__ out)
{
    __shared__ __align__(16) int4  lds_stage[2048];        // 32 KB codebook chunk
    __shared__ __align__(16) float lds_resid[TOKPB * 68];  // 17408 B persistent residual
    __shared__ float lds_csqh[CHUNK];
    __shared__ int4  lds_cand[8 * 16];
    __shared__ int   lds_pick[TOKPB];

    const int tid   = threadIdx.x;
    const int lane  = tid & 63;
    const int wave  = tid >> 6;          // 0..7
    const int group = wave >> 1;         // 0..3
    const int half  = wave & 1;          // code half
    const int g     = lane >> 4;         // quad
    const int c     = lane & 15;
    const int ltok  = group * 16 + c;

    // ---- init: residual = x, into LDS ----
    if (half == 0) {
        const float4* xp = (const float4*)(x + (size_t)(blockIdx.x * TOKPB + ltok) * D);
        float* rr = lds_resid + ltok * 68;
        *(float4*)(rr + 8*g)      = xp[g*2];
        *(float4*)(rr + 8*g + 4)  = xp[g*2+1];
        *(float4*)(rr + 32 + 8*g) = xp[8+g*2];
        *(float4*)(rr + 36 + 8*g) = xp[8+g*2+1];
    }

    // static LDS base for B-fragment reads (compile-time ds_read offsets)
    const char* bp = (const char*)lds_stage + (c << 4) + (g << 11) + (half << 10);
    const unsigned code_wc = (unsigned)(half * 64 + c);

    for (int q = 0; q < NQ; ++q) {
        __syncthreads();   // residual init / previous q's update visible

        // ---- A-split: read own token's 16 dims from LDS, split to bf16 hi/lo ----
        short8 ah0, al0, ah1, al1;
        {
            const float* rr = lds_resid + ltok * 68;
            float4 f0 = *(const float4*)(rr + 8*g);
            float4 f1 = *(const float4*)(rr + 8*g + 4);
            float4 f2 = *(const float4*)(rr + 32 + 8*g);
            float4 f3 = *(const float4*)(rr + 36 + 8*g);
            const float* fv0 = (const float*)&f0;
            const float* fv1 = (const float*)&f1;
            const float* fv2 = (const float*)&f2;
            const float* fv3 = (const float*)&f3;
            #pragma unroll
            for (int j = 0; j < 4; ++j) {
                float a = fv0[j], b = fv1[j], e = fv2[j], f = fv3[j];
                unsigned ha = bf16_rne_bits(a);
                unsigned hbv = bf16_rne_bits(b);
                unsigned he = bf16_rne_bits(e);
                unsigned hf = bf16_rne_bits(f);
                ah0[j]   = (short)ha;  ah0[4+j] = (short)hbv;
                ah1[j]   = (short)he;  ah1[4+j] = (short)hf;
                al0[j]   = (short)bf16_rne_bits(a - __uint_as_float(ha  << 16));
                al0[4+j] = (short)bf16_rne_bits(b - __uint_as_float(hbv << 16));
                al1[j]   = (short)bf16_rne_bits(e - __uint_as_float(he  << 16));
                al1[4+j] = (short)bf16_rne_bits(f - __uint_as_float(hf  << 16));
            }
        }

        // packed top-3 (ascending u32; positive-float bits are order-isomorphic)
        unsigned t1[4], t2[4], t3[4];
        #pragma unroll
        for (int r = 0; r < 4; ++r) { t1[r] = 0xFFFFFFFFu; t2[r] = 0xFFFFFFFFu; t3[r] = 0xFFFFFFFFu; }

        for (int ch = 0; ch < NCHUNK; ++ch) {
            __syncthreads();   // previous chunk fully consumed
            {
                const int4* src = ws_cb + (size_t)(q * NCHUNK + ch) * 2048 + tid;
                LDS_AS char* ldst = (LDS_AS char*)lds_stage + tid * 16;
                #pragma unroll
                for (int t = 0; t < 4; ++t) {
                    __builtin_amdgcn_global_load_lds(
                        (const GLOBAL_AS unsigned int*)(src + t * TPB),
                        (LDS_AS unsigned int*)(ldst + t * TPB * 16), 16, 0, 0);
                }
                if (tid < CHUNK) {
                    __builtin_amdgcn_global_load_lds(
                        (const GLOBAL_AS unsigned int*)(ws_csq + 8192 + q * KCODES + ch * CHUNK + tid),
                        (LDS_AS unsigned int*)(&lds_csqh[tid]), 4, 0, 0);
                }
            }
            __syncthreads();   // drains vmcnt -> LDS visible

            #pragma unroll
            for (int tt = 0; tt < 4; ++tt) {
                short8 bh0 = *(const short8*)(bp + tt * 256);
                short8 bh1 = *(const short8*)(bp + 8192  + tt * 256);
                short8 bl0 = *(const short8*)(bp + 16384 + tt * 256);
                short8 bl1 = *(const short8*)(bp + 24576 + tt * 256);
                const float sd = lds_csqh[half * 64 + tt * 16 + c];
                f32x4 acc = {sd, sd, sd, sd};
                acc = __builtin_amdgcn_mfma_f32_16x16x32_bf16(ah0, bh0, acc, 0, 0, 0);
                acc = __builtin_amdgcn_mfma_f32_16x16x32_bf16(ah1, bh1, acc, 0, 0, 0);
                acc = __builtin_amdgcn_mfma_f32_16x16x32_bf16(al0, bh0, acc, 0, 0, 0);
                acc = __builtin_amdgcn_mfma_f32_16x16x32_bf16(ah0, bl0, acc, 0, 0, 0);
                acc = __builtin_amdgcn_mfma_f32_16x16x32_bf16(al1, bh1, acc, 0, 0, 0);
                acc = __builtin_amdgcn_mfma_f32_16x16x32_bf16(ah1, bl1, acc, 0, 0, 0);
                acc = __builtin_amdgcn_mfma_f32_16x16x32_bf16(al0, bl0, acc, 0, 0, 0);
                acc = __builtin_amdgcn_mfma_f32_16x16x32_bf16(al1, bl1, acc, 0, 0, 0);

                const unsigned codev = code_wc + (unsigned)(ch * 128 + tt * 16);
                #pragma unroll
                for (int r = 0; r < 4; ++r) {
                    unsigned p = (__float_as_uint(acc[r]) & 0xFFFFFC00u) | codev;
                    unsigned n2 = umn(t2[r], umx(t1[r], p));
                    unsigned n3 = umn(t3[r], umx(t2[r], p));
                    t1[r] = umn(t1[r], p);
                    t2[r] = n2;
                    t3[r] = n3;
                }
            }
        }

        // ---- cross-lane top-3 merge over the 16 c-lanes (u32 sorted-triple network) ----
        #pragma unroll
        for (int s = 1; s <= 8; s <<= 1) {
            #pragma unroll
            for (int r = 0; r < 4; ++r) {
                unsigned o1 = (unsigned)__shfl_xor((int)t1[r], s);
                unsigned o2 = (unsigned)__shfl_xor((int)t2[r], s);
                unsigned o3 = (unsigned)__shfl_xor((int)t3[r], s);
                unsigned x1 = umn(t1[r], o1), y1 = umx(t1[r], o1);
                unsigned x2 = umn(t2[r], o2), y2 = umx(t2[r], o2);
                unsigned x3 = umn(t3[r], o3);
                t1[r] = x1;
                t3[r] = umed3(y1, x2, umn(y2, x3));
                t2[r] = umn(y1, x2);
            }
        }

        // ---- publish per-half candidates ----
        __syncthreads();                     // all waves done reading the chunk buffer
        if (c == 0) {
            #pragma unroll
            for (int r = 0; r < 4; ++r)
                lds_cand[(group * 2 + half) * 16 + g * 4 + r] =
                    make_int4((int)t1[r], (int)t2[r], (int)t3[r], 0);
        }
        __syncthreads();

        // ---- cross-half merge + ALWAYS-ON exact refinement over top-3 ----
        {
            const int sel = lane >> 4;         // 0,1,2 active; 3 duplicates m3 harmlessly
            const int t   = lane & 15;
            const int4 A = lds_cand[(group * 2 + 0) * 16 + t];
            const int4 B = lds_cand[(group * 2 + 1) * 16 + t];
            unsigned a1 = (unsigned)A.x, a2 = (unsigned)A.y, a3 = (unsigned)A.z;
            unsigned b1 = (unsigned)B.x, b2 = (unsigned)B.y, b3 = (unsigned)B.z;
            unsigned x1 = umn(a1, b1), y1 = umx(a1, b1);
            unsigned x2 = umn(a2, b2), y2 = umx(a2, b2);
            unsigned x3 = umn(a3, b3);
            unsigned m1 = x1;
            unsigned m2 = umn(y1, x2);
            unsigned m3 = umed3(y1, x2, umn(y2, x3));
            unsigned psel = (sel == 0) ? m1 : ((sel == 1) ? m2 : m3);
            const int cd = (int)(psel & 1023u);

            // exact fp32 distance, bit-identical comparator arithmetic to rounds 3/4/6
            const float4* rrv = (const float4*)(lds_resid + (group * 16 + t) * 68);
            const float4* cpv = (const float4*)(cb + ((size_t)(q * KCODES + cd)) * D);
            float ax = 0.f, ay = 0.f, az = 0.f, aw = 0.f;
            #pragma unroll
            for (int j = 0; j < 16; ++j) {
                float4 rv = rrv[j];
                float4 cv = cpv[j];
                ax = fmaf(rv.x, cv.x, ax);
                ay = fmaf(rv.y, cv.y, ay);
                az = fmaf(rv.z, cv.z, az);
                aw = fmaf(rv.w, cv.w, aw);
            }
            float dot = (ax + ay) + (az + aw);
            float dd = fmaf(dot, -2.0f, ws_csq[q * KCODES + cd]);

            float d0 = __shfl(dd, t);
            float d1 = __shfl(dd, t + 16);
            float d2 = __shfl(dd, t + 32);
            int cc0 = (int)(m1 & 1023u);
            int cc1 = (int)(m2 & 1023u);
            int cc2 = (int)(m3 & 1023u);
            float db = d0; int pick = cc0;
            if (d1 < db || (d1 == db && cc1 < pick)) { db = d1; pick = cc1; }
            if (d2 < db || (d2 == db && cc2 < pick)) { db = d2; pick = cc2; }
            if (half == 0 && sel == 0) lds_pick[group * 16 + t] = pick;
        }
        __syncthreads();

        // ---- residual update in LDS: resid -= cb[q][ifin] (half 0 only) ----
        if (half == 0) {
            const int ifin = lds_pick[ltok];
            const float4* cp = (const float4*)(cb + ((size_t)(q * KCODES + ifin)) * D);
            float* rr = lds_resid + ltok * 68;
            float4 c0 = cp[g*2], c1 = cp[g*2+1], c2 = cp[8+g*2], c3 = cp[8+g*2+1];
            float4 r0 = *(float4*)(rr + 8*g);
            float4 r1 = *(float4*)(rr + 8*g + 4);
            float4 r2 = *(float4*)(rr + 32 + 8*g);
            float4 r3 = *(float4*)(rr + 36 + 8*g);
            r0.x -= c0.x; r0.y -= c0.y; r0.z -= c0.z; r0.w -= c0.w;
            r1.x -= c1.x; r1.y -= c1.y; r1.z -= c1.z; r1.w -= c1.w;
            r2.x -= c2.x; r2.y -= c2.y; r2.z -= c2.z; r2.w -= c2.w;
            r3.x -= c3.x; r3.y -= c3.y; r3.z -= c3.z; r3.w -= c3.w;
            *(float4*)(rr + 8*g)      = r0;
            *(float4*)(rr + 8*g + 4)  = r1;
            *(float4*)(rr + 32 + 8*g) = r2;
            *(float4*)(rr + 36 + 8*g) = r3;
        }
    }

    // ---- epilogue: out = x - residual_final ----
    __syncthreads();
    if (half == 0) {
        const size_t base = (size_t)(blockIdx.x * TOKPB + ltok) * D;
        const float4* xp = (const float4*)(x + base);
        float4* op = (float4*)(out + base);
        const float* rr = lds_resid + ltok * 68;
        float4 r0 = *(const float4*)(rr + 8*g);
        float4 r1 = *(const float4*)(rr + 8*g + 4);
        float4 r2 = *(const float4*)(rr + 32 + 8*g);
        float4 r3 = *(const float4*)(rr + 36 + 8*g);
        float4 xv0 = xp[g*2], xv1 = xp[g*2+1], xv2 = xp[8+g*2], xv3 = xp[8+g*2+1];
        float4 o0, o1, o2, o3;
        o0.x = xv0.x - r0.x; o0.y = xv0.y - r0.y; o0.z = xv0.z - r0.z; o0.w = xv0.w - r0.w;
        o1.x = xv1.x - r1.x; o1.y = xv1.y - r1.y; o1.z = xv1.z - r1.z; o1.w = xv1.w - r1.w;
        o2.x = xv2.x - r2.x; o2.y = xv2.y - r2.y; o2.z = xv2.z - r2.z; o2.w = xv2.w - r2.w;
        o3.x = xv3.x - r3.x; o3.y = xv3.y - r3.y; o3.z = xv3.z - r3.z; o3.w = xv3.w - r3.w;
        op[g*2] = o0; op[g*2+1] = o1; op[8+g*2] = o2; op[8+g*2+1] = o3;
    }
}

extern "C" void kernel_launch(void* const* d_in, const int* in_sizes, int n_in,
                              void* d_out, int out_size, void* d_ws, size_t ws_size,
                              hipStream_t stream) {
    const float* x  = (const float*)d_in[0];
    const float* cb = (const float*)d_in[1];
    float* out = (float*)d_out;

    int4*  ws_cb   = (int4*)d_ws;                                      // 2 MB
    float* ws_csq  = (float*)((char*)d_ws + (size_t)2 * 1024 * 1024);  // 32 KB exact
    float* ws_csqh = ws_csq + 8192;                                    // 32 KB seed

    prep_cb <<<512, 256, 0, stream>>>(cb, ws_cb);
    prep_csq<<< 32, 256, 0, stream>>>(cb, ws_csq, ws_csqh);

    const int n_tokens = in_sizes[0] / D;            // 65536
    const int grid = n_tokens / TOKPB;               // 1024 blocks
    rvq_mfma<<<grid, TPB, 0, stream>>>(x, cb, ws_cb, ws_csq, out);
}

// Round 8
// 367.485 us; speedup vs baseline: 1.7764x; 1.2958x over previous
//
#include <hip/hip_runtime.h>

#define NQ 8
#define KCODES 1024
#define D 64
#define CHUNK 64
#define NCHUNK 16
#define TPB 256
#define TOKPB 128            // tokens per block = 4 waves x 32
#define BIAS 96.0f

using short8 = __attribute__((ext_vector_type(8))) short;
using f32x4  = __attribute__((ext_vector_type(4))) float;

#define GLOBAL_AS __attribute__((address_space(1)))
#define LDS_AS    __attribute__((address_space(3)))

static __device__ __forceinline__ unsigned bf16_rne_bits(float f) {
    unsigned u = __float_as_uint(f);
    return (u + 0x7fffu + ((u >> 16) & 1u)) >> 16;   // bf16 RNE bit pattern
}
static __device__ __forceinline__ unsigned umn(unsigned a, unsigned b) { return a < b ? a : b; }
static __device__ __forceinline__ unsigned umx(unsigned a, unsigned b) { return a > b ? a : b; }
static __device__ __forceinline__ unsigned umed3(unsigned a, unsigned b, unsigned c) {
    return umx(umn(a, b), umn(umx(a, b), c));
}

// ---------------- prologue 1: split NEGATED codebook into bf16 hi/lo granules ----------------
// ws_cb layout: [q][ch16][plane16][code64], plane = term*8 + kt*4 + g. Stores -c.
__global__ __launch_bounds__(256) void prep_cb(const float* __restrict__ cb,
                                               int4* __restrict__ ws_cb) {
    int id = blockIdx.x * 256 + threadIdx.x;       // 0 .. 131071
    int n_rel = id & 63;
    int plane = (id >> 6) & 15;
    int ch    = (id >> 10) & 15;
    int q     = id >> 14;
    int g = plane & 3, kt = (plane >> 2) & 1, term = plane >> 3;
    int n = ch * CHUNK + n_rel;
    const float* src = cb + ((size_t)(q * KCODES + n)) * D + kt * 32 + g * 8;
    union { short s[8]; int4 v; } u;
    #pragma unroll
    for (int j = 0; j < 8; ++j) {
        float f = -src[j];                         // NEGATED
        unsigned hb = bf16_rne_bits(f);
        if (term == 0) {
            u.s[j] = (short)hb;
        } else {
            float lo = f - __uint_as_float(hb << 16);
            u.s[j] = (short)bf16_rne_bits(lo);
        }
    }
    ws_cb[id] = u.v;
}

// ---------------- prologue 2: c_sq exact (refine) + seed (csq/2 + BIAS, approx) ----------------
__global__ __launch_bounds__(256) void prep_csq(const float* __restrict__ cb,
                                                float* __restrict__ ws_csq,
                                                float* __restrict__ ws_csqh) {
    int id = blockIdx.x * 256 + threadIdx.x;       // 0 .. 8191
    const float* c = cb + (size_t)id * D;
    float s0 = 0.f, s1 = 0.f, s2 = 0.f, s3 = 0.f;
    #pragma unroll
    for (int j = 0; j < 16; ++j) {
        s0 = fmaf(c[4*j+0], c[4*j+0], s0);
        s1 = fmaf(c[4*j+1], c[4*j+1], s1);
        s2 = fmaf(c[4*j+2], c[4*j+2], s2);
        s3 = fmaf(c[4*j+3], c[4*j+3], s3);
    }
    float cs = (s0 + s1) + (s2 + s3);
    ws_csq[id]  = cs;                // exact, refine comparator (bit-identical to r3..r7)
    ws_csqh[id] = 0.5f * cs + BIAS;  // approx seed: acc = seed - dot (always > 0)
}

// ---------------- main kernel ----------------
// Wave = 32 tokens (two 16-row MFMA A-tiles) x all 64 codes of each chunk.
__global__ __launch_bounds__(TPB, 4) void rvq_mfma(
    const float* __restrict__ x,
    const float* __restrict__ cb,
    const int4* __restrict__ ws_cb,
    const float* __restrict__ ws_csq,
    float* __restrict__ out)
{
    __shared__ __align__(16) int4  lds_stage[1024];        // 16 KB codebook chunk
    __shared__ __align__(16) float lds_resid[TOKPB * 68];  // 34816 B persistent residual
    __shared__ float    lds_csqh[CHUNK];                   // 256 B
    __shared__ unsigned lds_cand[TOKPB * 3];               // 1536 B packed top-3
    __shared__ int      lds_pick[TOKPB];                   // 512 B

    const int tid  = threadIdx.x;
    const int lane = tid & 63;
    const int wave = tid >> 6;          // 0..3
    const int g    = lane >> 4;         // quad
    const int c    = lane & 15;
    const int tok0 = blockIdx.x * TOKPB;

    // ---- init: residual = x, into LDS (2 threads per token) ----
    {
        const int t = tid >> 1, part = tid & 1;
        const float4* xp = (const float4*)(x + (size_t)(tok0 + t) * D + part * 32);
        float4* rr = (float4*)(lds_resid + t * 68 + part * 32);
        #pragma unroll
        for (int k2 = 0; k2 < 8; ++k2) rr[k2] = xp[k2];
    }

    // static LDS base for B-fragment reads (compile-time ds_read offsets)
    const char* bp = (const char*)lds_stage + (c << 4) + (g << 10);

    for (int q = 0; q < NQ; ++q) {
        __syncthreads();   // residual init / previous q's update visible

        // ---- A-split for the two 16-token sub-tiles ----
        short8 ah0[2], ah1[2], al0[2], al1[2];
        #pragma unroll
        for (int s = 0; s < 2; ++s) {
            const float* rr = lds_resid + (wave * 32 + s * 16 + c) * 68;
            float4 f0 = *(const float4*)(rr + 8 * g);
            float4 f1 = *(const float4*)(rr + 8 * g + 4);
            float4 f2 = *(const float4*)(rr + 32 + 8 * g);
            float4 f3 = *(const float4*)(rr + 36 + 8 * g);
            const float* v0 = (const float*)&f0;
            const float* v1 = (const float*)&f1;
            const float* v2 = (const float*)&f2;
            const float* v3 = (const float*)&f3;
            #pragma unroll
            for (int j = 0; j < 4; ++j) {
                float a = v0[j], b = v1[j], e = v2[j], f = v3[j];
                unsigned ha = bf16_rne_bits(a);
                unsigned hb = bf16_rne_bits(b);
                unsigned he = bf16_rne_bits(e);
                unsigned hf = bf16_rne_bits(f);
                ah0[s][j]   = (short)ha;  ah0[s][4+j] = (short)hb;
                ah1[s][j]   = (short)he;  ah1[s][4+j] = (short)hf;
                al0[s][j]   = (short)bf16_rne_bits(a - __uint_as_float(ha << 16));
                al0[s][4+j] = (short)bf16_rne_bits(b - __uint_as_float(hb << 16));
                al1[s][j]   = (short)bf16_rne_bits(e - __uint_as_float(he << 16));
                al1[s][4+j] = (short)bf16_rne_bits(f - __uint_as_float(hf << 16));
            }
        }

        // packed top-3 per (sub-tile, row) — ascending u32
        unsigned T1[2][4], T2[2][4], T3[2][4];
        #pragma unroll
        for (int s = 0; s < 2; ++s)
            #pragma unroll
            for (int r = 0; r < 4; ++r) { T1[s][r] = 0xFFFFFFFFu; T2[s][r] = 0xFFFFFFFFu; T3[s][r] = 0xFFFFFFFFu; }

        for (int ch = 0; ch < NCHUNK; ++ch) {
            __syncthreads();   // previous chunk fully consumed
            {
                const int4* src = ws_cb + (size_t)(q * NCHUNK + ch) * 1024 + tid;
                LDS_AS char* ldst = (LDS_AS char*)lds_stage + tid * 16;
                #pragma unroll
                for (int t = 0; t < 4; ++t) {
                    __builtin_amdgcn_global_load_lds(
                        (const GLOBAL_AS unsigned int*)(src + t * 256),
                        (LDS_AS unsigned int*)(ldst + t * 4096), 16, 0, 0);
                }
                if (tid < CHUNK) {
                    __builtin_amdgcn_global_load_lds(
                        (const GLOBAL_AS unsigned int*)(ws_csq + 8192 + q * KCODES + ch * CHUNK + tid),
                        (LDS_AS unsigned int*)(&lds_csqh[tid]), 4, 0, 0);
                }
            }
            __syncthreads();   // drains vmcnt -> LDS visible

            #pragma unroll
            for (int tt = 0; tt < 4; ++tt) {
                short8 bh0 = *(const short8*)(bp + tt * 256);
                short8 bh1 = *(const short8*)(bp + 4096  + tt * 256);
                short8 bl0 = *(const short8*)(bp + 8192  + tt * 256);
                short8 bl1 = *(const short8*)(bp + 12288 + tt * 256);
                const float sd = lds_csqh[tt * 16 + c];
                const unsigned codev = (unsigned)(ch * CHUNK + tt * 16 + c);
                #pragma unroll
                for (int s = 0; s < 2; ++s) {
                    f32x4 acc = {sd, sd, sd, sd};
                    acc = __builtin_amdgcn_mfma_f32_16x16x32_bf16(ah0[s], bh0, acc, 0, 0, 0);
                    acc = __builtin_amdgcn_mfma_f32_16x16x32_bf16(ah1[s], bh1, acc, 0, 0, 0);
                    acc = __builtin_amdgcn_mfma_f32_16x16x32_bf16(al0[s], bh0, acc, 0, 0, 0);
                    acc = __builtin_amdgcn_mfma_f32_16x16x32_bf16(ah0[s], bl0, acc, 0, 0, 0);
                    acc = __builtin_amdgcn_mfma_f32_16x16x32_bf16(al1[s], bh1, acc, 0, 0, 0);
                    acc = __builtin_amdgcn_mfma_f32_16x16x32_bf16(ah1[s], bl1, acc, 0, 0, 0);
                    // (al*bl dropped: ~5e-4 error << 7.8e-3 quant slack absorbed by top-3 refine)
                    #pragma unroll
                    for (int r = 0; r < 4; ++r) {
                        unsigned p = (__float_as_uint(acc[r]) & 0xFFFFFC00u) | codev;
                        unsigned n2 = umn(T2[s][r], umx(T1[s][r], p));
                        unsigned n3 = umn(T3[s][r], umx(T2[s][r], p));
                        T1[s][r] = umn(T1[s][r], p);
                        T2[s][r] = n2;
                        T3[s][r] = n3;
                    }
                }
            }
        }

        // ---- cross-lane top-3 merge over the 16 c-lanes ----
        #pragma unroll
        for (int st = 1; st <= 8; st <<= 1) {
            #pragma unroll
            for (int s = 0; s < 2; ++s) {
                #pragma unroll
                for (int r = 0; r < 4; ++r) {
                    unsigned o1 = (unsigned)__shfl_xor((int)T1[s][r], st);
                    unsigned o2 = (unsigned)__shfl_xor((int)T2[s][r], st);
                    unsigned o3 = (unsigned)__shfl_xor((int)T3[s][r], st);
                    unsigned x1 = umn(T1[s][r], o1), y1 = umx(T1[s][r], o1);
                    unsigned x2 = umn(T2[s][r], o2), y2 = umx(T2[s][r], o2);
                    unsigned x3 = umn(T3[s][r], o3);
                    T1[s][r] = x1;
                    T3[s][r] = umed3(y1, x2, umn(y2, x3));
                    T2[s][r] = umn(y1, x2);
                }
            }
        }

        // ---- publish candidates (each wave owns its 32 tokens) ----
        if (c == 0) {
            #pragma unroll
            for (int s = 0; s < 2; ++s)
                #pragma unroll
                for (int r = 0; r < 4; ++r) {
                    const int idx = (wave * 32 + s * 16 + g * 4 + r) * 3;
                    lds_cand[idx + 0] = T1[s][r];
                    lds_cand[idx + 1] = T2[s][r];
                    lds_cand[idx + 2] = T3[s][r];
                }
        }
        __syncthreads();

        // ---- ALWAYS-ON exact refinement over top-3 (2 passes of 16 tokens/wave) ----
        #pragma unroll
        for (int p = 0; p < 2; ++p) {
            const int t4  = lane >> 2;         // token within sub-tile
            const int sel = lane & 3;          // candidate slot (3 duplicates slot 2)
            const int row = wave * 32 + p * 16 + t4;
            const unsigned m1 = lds_cand[row * 3 + 0];
            const unsigned m2 = lds_cand[row * 3 + 1];
            const unsigned m3 = lds_cand[row * 3 + 2];
            const unsigned psel = (sel == 0) ? m1 : ((sel == 1) ? m2 : m3);
            const int cd = (int)(psel & 1023u);

            // exact fp32 distance, bit-identical comparator arithmetic to rounds 3..7
            const float4* rrv = (const float4*)(lds_resid + row * 68);
            const float4* cpv = (const float4*)(cb + ((size_t)(q * KCODES + cd)) * D);
            float ax = 0.f, ay = 0.f, az = 0.f, aw = 0.f;
            #pragma unroll
            for (int j = 0; j < 16; ++j) {
                float4 rv = rrv[j];
                float4 cv = cpv[j];
                ax = fmaf(rv.x, cv.x, ax);
                ay = fmaf(rv.y, cv.y, ay);
                az = fmaf(rv.z, cv.z, az);
                aw = fmaf(rv.w, cv.w, aw);
            }
            float dot = (ax + ay) + (az + aw);
            float dd = fmaf(dot, -2.0f, ws_csq[q * KCODES + cd]);

            const int base = lane & ~3;
            float d0 = __shfl(dd, base);
            float d1 = __shfl(dd, base + 1);
            float d2 = __shfl(dd, base + 2);
            int cc0 = (int)(m1 & 1023u);
            int cc1 = (int)(m2 & 1023u);
            int cc2 = (int)(m3 & 1023u);
            float db = d0; int pick = cc0;
            if (d1 < db || (d1 == db && cc1 < pick)) { db = d1; pick = cc1; }
            if (d2 < db || (d2 == db && cc2 < pick)) { db = d2; pick = cc2; }
            if (sel == 0) lds_pick[row] = pick;
        }
        __syncthreads();

        // ---- residual update in LDS: resid -= cb[q][ifin] (2 threads per token) ----
        {
            const int t = tid >> 1, part = tid & 1;
            const int ifin = lds_pick[t];
            const float4* cp = (const float4*)(cb + ((size_t)(q * KCODES + ifin)) * D + part * 32);
            float4* rr = (float4*)(lds_resid + t * 68 + part * 32);
            #pragma unroll
            for (int k2 = 0; k2 < 8; ++k2) {
                float4 rv = rr[k2], cv = cp[k2];
                rv.x -= cv.x; rv.y -= cv.y; rv.z -= cv.z; rv.w -= cv.w;
                rr[k2] = rv;
            }
        }
    }

    // ---- epilogue: out = x - residual_final ----
    __syncthreads();
    {
        const int t = tid >> 1, part = tid & 1;
        const float4* xp = (const float4*)(x + (size_t)(tok0 + t) * D + part * 32);
        const float4* rr = (const float4*)(lds_resid + t * 68 + part * 32);
        float4* op = (float4*)(out + (size_t)(tok0 + t) * D + part * 32);
        #pragma unroll
        for (int k2 = 0; k2 < 8; ++k2) {
            float4 xv = xp[k2], rv = rr[k2];
            float4 o;
            o.x = xv.x - rv.x; o.y = xv.y - rv.y;
            o.z = xv.z - rv.z; o.w = xv.w - rv.w;
            op[k2] = o;
        }
    }
}

extern "C" void kernel_launch(void* const* d_in, const int* in_sizes, int n_in,
                              void* d_out, int out_size, void* d_ws, size_t ws_size,
                              hipStream_t stream) {
    const float* x  = (const float*)d_in[0];
    const float* cb = (const float*)d_in[1];
    float* out = (float*)d_out;

    int4*  ws_cb   = (int4*)d_ws;                                      // 2 MB
    float* ws_csq  = (float*)((char*)d_ws + (size_t)2 * 1024 * 1024);  // 32 KB exact
    float* ws_csqh = ws_csq + 8192;                                    // 32 KB seed (= ws_csq+8192)

    prep_cb <<<512, 256, 0, stream>>>(cb, ws_cb);
    prep_csq<<< 32, 256, 0, stream>>>(cb, ws_csq, ws_csqh);

    const int n_tokens = in_sizes[0] / D;            // 65536
    const int grid = n_tokens / TOKPB;               // 512 blocks
    rvq_mfma<<<grid, TPB, 0, stream>>>(x, cb, ws_cb, ws_csq, out);
}

// Round 9
// 352.243 us; speedup vs baseline: 1.8532x; 1.0433x over previous
//
#include <hip/hip_runtime.h>

#define NQ 8
#define KCODES 1024
#define D 64
#define CHUNK 64
#define NCHUNK 16
#define TPB 256
#define TOKPB 64             // tokens per block = 2 groups x 32
#define BIAS 96.0f

using short8 = __attribute__((ext_vector_type(8))) short;
using f32x4  = __attribute__((ext_vector_type(4))) float;

#define GLOBAL_AS __attribute__((address_space(1)))
#define LDS_AS    __attribute__((address_space(3)))

static __device__ __forceinline__ unsigned bf16_rne_bits(float f) {
    unsigned u = __float_as_uint(f);
    return (u + 0x7fffu + ((u >> 16) & 1u)) >> 16;   // bf16 RNE bit pattern
}
static __device__ __forceinline__ unsigned umn(unsigned a, unsigned b) { return a < b ? a : b; }
static __device__ __forceinline__ unsigned umx(unsigned a, unsigned b) { return a > b ? a : b; }
static __device__ __forceinline__ unsigned umed3(unsigned a, unsigned b, unsigned c) {
    return umx(umn(a, b), umn(umx(a, b), c));
}

// ---------------- prologue 1: split NEGATED codebook into bf16 hi/lo granules ----------------
// ws_cb layout: [q][ch16][plane16][code64], plane = term*8 + kt*4 + g. Stores -c.
__global__ __launch_bounds__(256) void prep_cb(const float* __restrict__ cb,
                                               int4* __restrict__ ws_cb) {
    int id = blockIdx.x * 256 + threadIdx.x;       // 0 .. 131071
    int n_rel = id & 63;
    int plane = (id >> 6) & 15;
    int ch    = (id >> 10) & 15;
    int q     = id >> 14;
    int g = plane & 3, kt = (plane >> 2) & 1, term = plane >> 3;
    int n = ch * CHUNK + n_rel;
    const float* src = cb + ((size_t)(q * KCODES + n)) * D + kt * 32 + g * 8;
    union { short s[8]; int4 v; } u;
    #pragma unroll
    for (int j = 0; j < 8; ++j) {
        float f = -src[j];                         // NEGATED
        unsigned hb = bf16_rne_bits(f);
        if (term == 0) {
            u.s[j] = (short)hb;
        } else {
            float lo = f - __uint_as_float(hb << 16);
            u.s[j] = (short)bf16_rne_bits(lo);
        }
    }
    ws_cb[id] = u.v;
}

// ---------------- prologue 2: c_sq exact (refine) + seed (csq/2 + BIAS, approx) ----------------
__global__ __launch_bounds__(256) void prep_csq(const float* __restrict__ cb,
                                                float* __restrict__ ws_csq,
                                                float* __restrict__ ws_csqh) {
    int id = blockIdx.x * 256 + threadIdx.x;       // 0 .. 8191
    const float* c = cb + (size_t)id * D;
    float s0 = 0.f, s1 = 0.f, s2 = 0.f, s3 = 0.f;
    #pragma unroll
    for (int j = 0; j < 16; ++j) {
        s0 = fmaf(c[4*j+0], c[4*j+0], s0);
        s1 = fmaf(c[4*j+1], c[4*j+1], s1);
        s2 = fmaf(c[4*j+2], c[4*j+2], s2);
        s3 = fmaf(c[4*j+3], c[4*j+3], s3);
    }
    float cs = (s0 + s1) + (s2 + s3);
    ws_csq[id]  = cs;                // exact, refine comparator (bit-identical to r3..r8)
    ws_csqh[id] = 0.5f * cs + BIAS;  // approx seed: acc = seed - dot (always > 0)
}

// ---------------- main kernel ----------------
// Wave (group, half) = 32 tokens x 32 codes of each 64-chunk. 4 blocks/CU, 16 waves/CU.
__global__ __launch_bounds__(TPB, 4) void rvq_mfma(
    const float* __restrict__ x,
    const float* __restrict__ cb,
    const int4* __restrict__ ws_cb,
    const float* __restrict__ ws_csq,
    float* __restrict__ out)
{
    __shared__ __align__(16) int4  lds_stage[1024];        // 16 KB codebook chunk
    __shared__ __align__(16) float lds_resid[TOKPB * 68];  // 17408 B persistent residual
    __shared__ float    lds_csqh[CHUNK];                   // 256 B
    __shared__ unsigned lds_cand[2][TOKPB * 3];            // 1536 B packed top-3 per half
    __shared__ int      lds_pick[TOKPB];                   // 256 B

    const int tid   = threadIdx.x;
    const int lane  = tid & 63;
    const int wave  = tid >> 6;          // 0..3
    const int group = wave >> 1;         // 0..1 (token group of 32)
    const int half  = wave & 1;          // code half (tt = half*2 .. half*2+1)
    const int g     = lane >> 4;         // quad
    const int c     = lane & 15;
    const int tok0  = blockIdx.x * TOKPB;

    // ---- init: residual = x, into LDS (4 threads per token) ----
    {
        const int t = tid >> 2, part = tid & 3;
        const float4* xp = (const float4*)(x + (size_t)(tok0 + t) * D + part * 16);
        float4* rr = (float4*)(lds_resid + t * 68 + part * 16);
        #pragma unroll
        for (int k2 = 0; k2 < 4; ++k2) rr[k2] = xp[k2];
    }

    // static LDS base for B-fragment reads (compile-time ds_read offsets)
    const char* bp = (const char*)lds_stage + (c << 4) + (g << 10) + half * 512;

    for (int q = 0; q < NQ; ++q) {
        __syncthreads();   // residual init / previous q's update visible

        // ---- A-split for the group's two 16-token sub-tiles ----
        short8 ah0[2], ah1[2], al0[2], al1[2];
        #pragma unroll
        for (int s = 0; s < 2; ++s) {
            const float* rr = lds_resid + (group * 32 + s * 16 + c) * 68;
            float4 f0 = *(const float4*)(rr + 8 * g);
            float4 f1 = *(const float4*)(rr + 8 * g + 4);
            float4 f2 = *(const float4*)(rr + 32 + 8 * g);
            float4 f3 = *(const float4*)(rr + 36 + 8 * g);
            const float* v0 = (const float*)&f0;
            const float* v1 = (const float*)&f1;
            const float* v2 = (const float*)&f2;
            const float* v3 = (const float*)&f3;
            #pragma unroll
            for (int j = 0; j < 4; ++j) {
                float a = v0[j], b = v1[j], e = v2[j], f = v3[j];
                unsigned ha = bf16_rne_bits(a);
                unsigned hb = bf16_rne_bits(b);
                unsigned he = bf16_rne_bits(e);
                unsigned hf = bf16_rne_bits(f);
                ah0[s][j]   = (short)ha;  ah0[s][4+j] = (short)hb;
                ah1[s][j]   = (short)he;  ah1[s][4+j] = (short)hf;
                al0[s][j]   = (short)bf16_rne_bits(a - __uint_as_float(ha << 16));
                al0[s][4+j] = (short)bf16_rne_bits(b - __uint_as_float(hb << 16));
                al1[s][j]   = (short)bf16_rne_bits(e - __uint_as_float(he << 16));
                al1[s][4+j] = (short)bf16_rne_bits(f - __uint_as_float(hf << 16));
            }
        }

        // packed top-3 per (sub-tile, row) — ascending u32
        unsigned T1[2][4], T2[2][4], T3[2][4];
        #pragma unroll
        for (int s = 0; s < 2; ++s)
            #pragma unroll
            for (int r = 0; r < 4; ++r) { T1[s][r] = 0xFFFFFFFFu; T2[s][r] = 0xFFFFFFFFu; T3[s][r] = 0xFFFFFFFFu; }

        for (int ch = 0; ch < NCHUNK; ++ch) {
            __syncthreads();   // previous chunk fully consumed
            {
                const int4* src = ws_cb + (size_t)(q * NCHUNK + ch) * 1024 + tid;
                LDS_AS char* ldst = (LDS_AS char*)lds_stage + tid * 16;
                #pragma unroll
                for (int t = 0; t < 4; ++t) {
                    __builtin_amdgcn_global_load_lds(
                        (const GLOBAL_AS unsigned int*)(src + t * 256),
                        (LDS_AS unsigned int*)(ldst + t * 4096), 16, 0, 0);
                }
                if (tid < CHUNK) {
                    __builtin_amdgcn_global_load_lds(
                        (const GLOBAL_AS unsigned int*)(ws_csq + 8192 + q * KCODES + ch * CHUNK + tid),
                        (LDS_AS unsigned int*)(&lds_csqh[tid]), 4, 0, 0);
                }
            }
            __syncthreads();   // drains vmcnt -> LDS visible

            #pragma unroll
            for (int i = 0; i < 2; ++i) {        // this half's two 16-code tiles
                short8 bh0 = *(const short8*)(bp + i * 256);
                short8 bh1 = *(const short8*)(bp + 4096  + i * 256);
                short8 bl0 = *(const short8*)(bp + 8192  + i * 256);
                short8 bl1 = *(const short8*)(bp + 12288 + i * 256);
                const float sd = lds_csqh[(half * 2 + i) * 16 + c];
                const unsigned codev = (unsigned)(ch * CHUNK + (half * 2 + i) * 16 + c);
                #pragma unroll
                for (int s = 0; s < 2; ++s) {
                    f32x4 acc = {sd, sd, sd, sd};
                    acc = __builtin_amdgcn_mfma_f32_16x16x32_bf16(ah0[s], bh0, acc, 0, 0, 0);
                    acc = __builtin_amdgcn_mfma_f32_16x16x32_bf16(ah1[s], bh1, acc, 0, 0, 0);
                    acc = __builtin_amdgcn_mfma_f32_16x16x32_bf16(al0[s], bh0, acc, 0, 0, 0);
                    acc = __builtin_amdgcn_mfma_f32_16x16x32_bf16(ah0[s], bl0, acc, 0, 0, 0);
                    acc = __builtin_amdgcn_mfma_f32_16x16x32_bf16(al1[s], bh1, acc, 0, 0, 0);
                    acc = __builtin_amdgcn_mfma_f32_16x16x32_bf16(ah1[s], bl1, acc, 0, 0, 0);
                    #pragma unroll
                    for (int r = 0; r < 4; ++r) {
                        unsigned p = (__float_as_uint(acc[r]) & 0xFFFFFC00u) | codev;
                        unsigned n2 = umn(T2[s][r], umx(T1[s][r], p));
                        unsigned n3 = umn(T3[s][r], umx(T2[s][r], p));
                        T1[s][r] = umn(T1[s][r], p);
                        T2[s][r] = n2;
                        T3[s][r] = n3;
                    }
                }
            }
        }

        // ---- cross-lane top-3 merge over the 16 c-lanes ----
        #pragma unroll
        for (int st = 1; st <= 8; st <<= 1) {
            #pragma unroll
            for (int s = 0; s < 2; ++s) {
                #pragma unroll
                for (int r = 0; r < 4; ++r) {
                    unsigned o1 = (unsigned)__shfl_xor((int)T1[s][r], st);
                    unsigned o2 = (unsigned)__shfl_xor((int)T2[s][r], st);
                    unsigned o3 = (unsigned)__shfl_xor((int)T3[s][r], st);
                    unsigned x1 = umn(T1[s][r], o1), y1 = umx(T1[s][r], o1);
                    unsigned x2 = umn(T2[s][r], o2), y2 = umx(T2[s][r], o2);
                    unsigned x3 = umn(T3[s][r], o3);
                    T1[s][r] = x1;
                    T3[s][r] = umed3(y1, x2, umn(y2, x3));
                    T2[s][r] = umn(y1, x2);
                }
            }
        }

        // ---- publish per-half candidates ----
        if (c == 0) {
            #pragma unroll
            for (int s = 0; s < 2; ++s)
                #pragma unroll
                for (int r = 0; r < 4; ++r) {
                    const int idx = (group * 32 + s * 16 + g * 4 + r) * 3;
                    lds_cand[half][idx + 0] = T1[s][r];
                    lds_cand[half][idx + 1] = T2[s][r];
                    lds_cand[half][idx + 2] = T3[s][r];
                }
        }
        __syncthreads();

        // ---- cross-half merge + ALWAYS-ON exact refinement (each wave: 16 tokens) ----
        {
            const int t4  = lane >> 2;          // token within sub-tile
            const int sel = lane & 3;           // candidate slot (3 duplicates slot 2)
            const int row = group * 32 + half * 16 + t4;
            unsigned a1 = lds_cand[0][row * 3 + 0];
            unsigned a2 = lds_cand[0][row * 3 + 1];
            unsigned a3 = lds_cand[0][row * 3 + 2];
            unsigned b1 = lds_cand[1][row * 3 + 0];
            unsigned b2 = lds_cand[1][row * 3 + 1];
            unsigned b3 = lds_cand[1][row * 3 + 2];
            unsigned x1 = umn(a1, b1), y1 = umx(a1, b1);
            unsigned x2 = umn(a2, b2), y2 = umx(a2, b2);
            unsigned x3 = umn(a3, b3);
            unsigned m1 = x1;
            unsigned m2 = umn(y1, x2);
            unsigned m3 = umed3(y1, x2, umn(y2, x3));
            const unsigned psel = (sel == 0) ? m1 : ((sel == 1) ? m2 : m3);
            const int cd = (int)(psel & 1023u);

            // exact fp32 distance, bit-identical comparator arithmetic to rounds 3..8
            const float4* rrv = (const float4*)(lds_resid + row * 68);
            const float4* cpv = (const float4*)(cb + ((size_t)(q * KCODES + cd)) * D);
            float ax = 0.f, ay = 0.f, az = 0.f, aw = 0.f;
            #pragma unroll
            for (int j = 0; j < 16; ++j) {
                float4 rv = rrv[j];
                float4 cv = cpv[j];
                ax = fmaf(rv.x, cv.x, ax);
                ay = fmaf(rv.y, cv.y, ay);
                az = fmaf(rv.z, cv.z, az);
                aw = fmaf(rv.w, cv.w, aw);
            }
            float dot = (ax + ay) + (az + aw);
            float dd = fmaf(dot, -2.0f, ws_csq[q * KCODES + cd]);

            const int base = lane & ~3;
            float d0 = __shfl(dd, base);
            float d1 = __shfl(dd, base + 1);
            float d2 = __shfl(dd, base + 2);
            int cc0 = (int)(m1 & 1023u);
            int cc1 = (int)(m2 & 1023u);
            int cc2 = (int)(m3 & 1023u);
            float db = d0; int pick = cc0;
            if (d1 < db || (d1 == db && cc1 < pick)) { db = d1; pick = cc1; }
            if (d2 < db || (d2 == db && cc2 < pick)) { db = d2; pick = cc2; }
            if (sel == 0) lds_pick[row] = pick;
        }
        __syncthreads();

        // ---- residual update in LDS: resid -= cb[q][ifin] (4 threads per token) ----
        {
            const int t = tid >> 2, part = tid & 3;
            const int ifin = lds_pick[t];
            const float4* cp = (const float4*)(cb + ((size_t)(q * KCODES + ifin)) * D + part * 16);
            float4* rr = (float4*)(lds_resid + t * 68 + part * 16);
            #pragma unroll
            for (int k2 = 0; k2 < 4; ++k2) {
                float4 rv = rr[k2], cv = cp[k2];
                rv.x -= cv.x; rv.y -= cv.y; rv.z -= cv.z; rv.w -= cv.w;
                rr[k2] = rv;
            }
        }
    }

    // ---- epilogue: out = x - residual_final (4 threads per token) ----
    __syncthreads();
    {
        const int t = tid >> 2, part = tid & 3;
        const float4* xp = (const float4*)(x + (size_t)(tok0 + t) * D + part * 16);
        const float4* rr = (const float4*)(lds_resid + t * 68 + part * 16);
        float4* op = (float4*)(out + (size_t)(tok0 + t) * D + part * 16);
        #pragma unroll
        for (int k2 = 0; k2 < 4; ++k2) {
            float4 xv = xp[k2], rv = rr[k2];
            float4 o;
            o.x = xv.x - rv.x; o.y = xv.y - rv.y;
            o.z = xv.z - rv.z; o.w = xv.w - rv.w;
            op[k2] = o;
        }
    }
}

extern "C" void kernel_launch(void* const* d_in, const int* in_sizes, int n_in,
                              void* d_out, int out_size, void* d_ws, size_t ws_size,
                              hipStream_t stream) {
    const float* x  = (const float*)d_in[0];
    const float* cb = (const float*)d_in[1];
    float* out = (float*)d_out;

    int4*  ws_cb   = (int4*)d_ws;                                      // 2 MB
    float* ws_csq  = (float*)((char*)d_ws + (size_t)2 * 1024 * 1024);  // 32 KB exact
    float* ws_csqh = ws_csq + 8192;                                    // 32 KB seed (= ws_csq+8192)

    prep_cb <<<512, 256, 0, stream>>>(cb, ws_cb);
    prep_csq<<< 32, 256, 0, stream>>>(cb, ws_csq, ws_csqh);

    const int n_tokens = in_sizes[0] / D;            // 65536
    const int grid = n_tokens / TOKPB;               // 1024 blocks
    rvq_mfma<<<grid, TPB, 0, stream>>>(x, cb, ws_cb, ws_csq, out);
}